// Round 1
// baseline (267.369 us; speedup 1.0000x reference)
//
#include <hip/hip_runtime.h>

// HenonLayer: 4 iterations of
//   t = tanh(Y @ W_in + b_in)                    (B,64)
//   grad = ((1-t*t) * W_out[:,0]) @ W_in.T       (B,2)
//   X' = Y + eta ; Y' = -X + grad                (eps = 1)
// out = concat([X, Y], 1), float32. B = 2e6, DIM = 2, NI = 64.
//
// Math trick: with u = e^{2a}, r = 1/(1+u):  1 - tanh(a)^2 = 4 r (1-r).
// So s = r - r^2 and grad_j = sum_i s_i * (4*W_out_i*W_in[j,i]).
// The 2*log2(e) exp2-scale is folded into the packed weights, so the
// inner loop is: 2 FMA (pre-act), v_exp_f32, add, v_rcp_f32, 1 FMA (s),
// 2 FMA (grad) per neuron. Saturation is automatic (u=inf -> r=0 -> s=0;
// u=0 -> r=1 -> s=0), no branches.

#define NI 64

__device__ __forceinline__ float sech_q(float p) {
  // p = 2*log2(e)*a ; returns r - r^2 = 0.25*(1 - tanh(a)^2)
  float u = __builtin_amdgcn_exp2f(p);          // e^{2a}
  float r = __builtin_amdgcn_rcpf(1.0f + u);    // 1/(1+u)
  return r - r * r;                             // one v_fma (neg modifier)
}

// Packed parameter table in d_ws (5*NI + 2 floats):
// [0:64)   w0p = K2*W_in[0][i]
// [64:128) w1p = K2*W_in[1][i]
// [128:192) bp = K2*b_in[i]
// [192:256) c0 = 4*W_out[i]*W_in[0][i]
// [256:320) c1 = 4*W_out[i]*W_in[1][i]
// [320], [321] = eta0, eta1
__global__ __launch_bounds__(64) void henon_prep(
    const float* __restrict__ W_in, const float* __restrict__ W_out,
    const float* __restrict__ b_in, const float* __restrict__ eta,
    float* __restrict__ P) {
  const float K2 = 2.88539008177792681f;  // 2*log2(e)
  int i = threadIdx.x;
  float w0 = W_in[i];
  float w1 = W_in[NI + i];
  P[i]          = K2 * w0;
  P[NI + i]     = K2 * w1;
  P[2 * NI + i] = K2 * b_in[i];
  float wo4 = 4.0f * W_out[i];
  P[3 * NI + i] = wo4 * w0;
  P[4 * NI + i] = wo4 * w1;
  if (i < 2) P[5 * NI + i] = eta[i];
}

__global__ __launch_bounds__(256) void henon_packed(
    const float4* __restrict__ z, const float* __restrict__ P,
    float4* __restrict__ out, int batch) {
  int idx = blockIdx.x * blockDim.x + threadIdx.x;
  int stride = gridDim.x * blockDim.x;
  float e0 = P[5 * NI], e1 = P[5 * NI + 1];
  for (int row = idx; row < batch; row += stride) {
    float4 v = z[row];
    float X0 = v.x, X1 = v.y, Y0 = v.z, Y1 = v.w;
    for (int it = 0; it < 4; ++it) {
      float g0 = 0.f, g1 = 0.f;
#pragma unroll
      for (int i = 0; i < NI; ++i) {
        // All P[] accesses are wave-uniform -> scalar loads (s_load).
        float p = fmaf(Y0, P[i], fmaf(Y1, P[NI + i], P[2 * NI + i]));
        float s = sech_q(p);
        g0 = fmaf(s, P[3 * NI + i], g0);
        g1 = fmaf(s, P[4 * NI + i], g1);
      }
      float nX0 = Y0 + e0, nX1 = Y1 + e1;
      Y0 = g0 - X0;
      Y1 = g1 - X1;
      X0 = nX0;
      X1 = nX1;
    }
    out[row] = make_float4(X0, X1, Y0, Y1);
  }
}

// Fallback if ws_size is too small for the packed table: same math with
// raw weights (+2 VALU/neuron: K2 scale and W_out mul; global 4x folded
// into the Y update).
__global__ __launch_bounds__(256) void henon_raw(
    const float4* __restrict__ z, const float* __restrict__ W_in,
    const float* __restrict__ W_out, const float* __restrict__ b_in,
    const float* __restrict__ eta, float4* __restrict__ out, int batch) {
  const float K2 = 2.88539008177792681f;
  int idx = blockIdx.x * blockDim.x + threadIdx.x;
  int stride = gridDim.x * blockDim.x;
  float e0 = eta[0], e1 = eta[1];
  for (int row = idx; row < batch; row += stride) {
    float4 v = z[row];
    float X0 = v.x, X1 = v.y, Y0 = v.z, Y1 = v.w;
    for (int it = 0; it < 4; ++it) {
      float g0 = 0.f, g1 = 0.f;
#pragma unroll
      for (int i = 0; i < NI; ++i) {
        float w0 = W_in[i], w1 = W_in[NI + i];
        float a = fmaf(Y0, w0, fmaf(Y1, w1, b_in[i]));
        float s = sech_q(a * K2);
        float sw = s * W_out[i];
        g0 = fmaf(sw, w0, g0);
        g1 = fmaf(sw, w1, g1);
      }
      float nX0 = Y0 + e0, nX1 = Y1 + e1;
      Y0 = fmaf(4.0f, g0, -X0);
      Y1 = fmaf(4.0f, g1, -X1);
      X0 = nX0;
      X1 = nX1;
    }
    out[row] = make_float4(X0, X1, Y0, Y1);
  }
}

extern "C" void kernel_launch(void* const* d_in, const int* in_sizes, int n_in,
                              void* d_out, int out_size, void* d_ws, size_t ws_size,
                              hipStream_t stream) {
  const float4* z = (const float4*)d_in[0];
  const float* W_in = (const float*)d_in[1];
  const float* W_out = (const float*)d_in[2];
  const float* b_in = (const float*)d_in[3];
  const float* eta = (const float*)d_in[4];
  float4* out = (float4*)d_out;

  int batch = in_sizes[0] / 4;  // 2,000,000 rows of float4
  int blocks = (batch + 255) / 256;

  if (ws_size >= (5 * NI + 2) * sizeof(float)) {
    float* P = (float*)d_ws;
    henon_prep<<<1, 64, 0, stream>>>(W_in, W_out, b_in, eta, P);
    henon_packed<<<blocks, 256, 0, stream>>>(z, P, out, batch);
  } else {
    henon_raw<<<blocks, 256, 0, stream>>>(z, W_in, W_out, b_in, eta, out, batch);
  }
}

// Round 2
// 250.697 us; speedup vs baseline: 1.0665x; 1.0665x over previous
//
#include <hip/hip_runtime.h>

// HenonLayer: 4x { t=tanh(Y@W_in+b); grad=((1-t^2)*W_out)@W_in.T; X'=Y+eta; Y'=-X+grad }
// B=2e6, DIM=2, NI=64, fp32.
//
// Round-2 changes vs round-1 (205us, VALUBusy 97%, 63cyc/wave-visit):
//  1. sech^2(a) = rcp(cosh^2(a)) with cosh^2 = degree-5 all-positive Taylor in
//     x=a^2 -> ONE transcendental per visit instead of exp2+rcp. Monotone >=1,
//     no clamps/branches, abs err <= ~3e-4.
//  2. 4 rows/thread as two float2 packs -> v_pk_fma_f32 opportunity, scalar
//     constant delivery amortized 4x, two chains to hide rcp latency.

#define NI 64

// cosh^2(a) = 1 + x + x^2/3 + 2x^3/45 + x^4/315 + 2x^5/14175,  x = a^2
#define D5 1.410934744e-4f
#define D4 3.174603175e-3f
#define D3 4.444444444e-2f
#define D2 3.333333333e-1f

__device__ __forceinline__ float2 bc(float s) { float2 r; r.x = s; r.y = s; return r; }
__device__ __forceinline__ float2 fma2(float2 a, float2 b, float2 c) {
  float2 r; r.x = fmaf(a.x, b.x, c.x); r.y = fmaf(a.y, b.y, c.y); return r;
}
__device__ __forceinline__ float2 mul2(float2 a, float2 b) {
  float2 r; r.x = a.x * b.x; r.y = a.y * b.y; return r;
}
__device__ __forceinline__ float2 add2(float2 a, float2 b) {
  float2 r; r.x = a.x + b.x; r.y = a.y + b.y; return r;
}
__device__ __forceinline__ float2 sub2(float2 a, float2 b) {
  float2 r; r.x = a.x - b.x; r.y = a.y - b.y; return r;
}
__device__ __forceinline__ float2 sech2_2(float2 a) {
  float2 x = mul2(a, a);
  float2 p = fma2(x, bc(D5), bc(D4));
  p = fma2(p, x, bc(D3));
  p = fma2(p, x, bc(D2));
  p = fma2(p, x, bc(1.0f));
  p = fma2(p, x, bc(1.0f));
  float2 s;
  s.x = __builtin_amdgcn_rcpf(p.x);
  s.y = __builtin_amdgcn_rcpf(p.y);
  return s;
}

// Packed table in d_ws (5*NI+2 floats):
// [0:64) w0 | [64:128) w1 | [128:192) b | [192:256) c0=W_out*w0 | [256:320) c1=W_out*w1 | eta0 eta1
__global__ __launch_bounds__(64) void henon_prep(
    const float* __restrict__ W_in, const float* __restrict__ W_out,
    const float* __restrict__ b_in, const float* __restrict__ eta,
    float* __restrict__ P) {
  int i = threadIdx.x;
  float w0 = W_in[i];
  float w1 = W_in[NI + i];
  P[i] = w0;
  P[NI + i] = w1;
  P[2 * NI + i] = b_in[i];
  float wo = W_out[i];
  P[3 * NI + i] = wo * w0;
  P[4 * NI + i] = wo * w1;
  if (i < 2) P[5 * NI + i] = eta[i];
}

__global__ __launch_bounds__(256) void henon4(
    const float4* __restrict__ z, const float* __restrict__ P,
    float4* __restrict__ out, int batch) {
  int tid = blockIdx.x * blockDim.x + threadIdx.x;
  int nthr = gridDim.x * blockDim.x;
  float e0 = P[5 * NI], e1 = P[5 * NI + 1];
  int ngroups = batch >> 2;

  for (int g = tid; g < ngroups; g += nthr) {
    int r = g << 2;
    float4 v0 = z[r], v1 = z[r + 1], v2 = z[r + 2], v3 = z[r + 3];
    // pack A = rows r,r+1 ; pack B = rows r+2,r+3
    float2 X0A = {v0.x, v1.x}, X1A = {v0.y, v1.y}, Y0A = {v0.z, v1.z}, Y1A = {v0.w, v1.w};
    float2 X0B = {v2.x, v3.x}, X1B = {v2.y, v3.y}, Y0B = {v2.z, v3.z}, Y1B = {v2.w, v3.w};

    for (int it = 0; it < 4; ++it) {
      float2 g0A = bc(0.f), g1A = bc(0.f), g0B = bc(0.f), g1B = bc(0.f);
#pragma unroll
      for (int i = 0; i < NI; ++i) {
        // Wave-uniform -> scalar loads; shared by all 4 rows.
        float w0 = P[i], w1 = P[NI + i], b = P[2 * NI + i];
        float c0 = P[3 * NI + i], c1 = P[4 * NI + i];
        float2 aA = fma2(Y0A, bc(w0), fma2(Y1A, bc(w1), bc(b)));
        float2 aB = fma2(Y0B, bc(w0), fma2(Y1B, bc(w1), bc(b)));
        float2 sA = sech2_2(aA);
        float2 sB = sech2_2(aB);
        g0A = fma2(sA, bc(c0), g0A);
        g1A = fma2(sA, bc(c1), g1A);
        g0B = fma2(sB, bc(c0), g0B);
        g1B = fma2(sB, bc(c1), g1B);
      }
      float2 nX0A = add2(Y0A, bc(e0)), nX1A = add2(Y1A, bc(e1));
      float2 nX0B = add2(Y0B, bc(e0)), nX1B = add2(Y1B, bc(e1));
      Y0A = sub2(g0A, X0A);
      Y1A = sub2(g1A, X1A);
      Y0B = sub2(g0B, X0B);
      Y1B = sub2(g1B, X1B);
      X0A = nX0A; X1A = nX1A; X0B = nX0B; X1B = nX1B;
    }
    out[r]     = make_float4(X0A.x, X1A.x, Y0A.x, Y1A.x);
    out[r + 1] = make_float4(X0A.y, X1A.y, Y0A.y, Y1A.y);
    out[r + 2] = make_float4(X0B.x, X1B.x, Y0B.x, Y1B.x);
    out[r + 3] = make_float4(X0B.y, X1B.y, Y0B.y, Y1B.y);
  }

  // Tail rows (batch % 4), scalar path.
  int tail = batch & 3;
  if (tail) {
    int row = (ngroups << 2) + tid;
    if (tid < tail) {
      float4 v = z[row];
      float X0 = v.x, X1 = v.y, Y0 = v.z, Y1 = v.w;
      for (int it = 0; it < 4; ++it) {
        float g0 = 0.f, g1 = 0.f;
        for (int i = 0; i < NI; ++i) {
          float a = fmaf(Y0, P[i], fmaf(Y1, P[NI + i], P[2 * NI + i]));
          float x = a * a;
          float p = fmaf(x, D5, D4);
          p = fmaf(p, x, D3);
          p = fmaf(p, x, D2);
          p = fmaf(p, x, 1.0f);
          p = fmaf(p, x, 1.0f);
          float s = __builtin_amdgcn_rcpf(p);
          g0 = fmaf(s, P[3 * NI + i], g0);
          g1 = fmaf(s, P[4 * NI + i], g1);
        }
        float nX0 = Y0 + e0, nX1 = Y1 + e1;
        Y0 = g0 - X0;
        Y1 = g1 - X1;
        X0 = nX0;
        X1 = nX1;
      }
      out[row] = make_float4(X0, X1, Y0, Y1);
    }
  }
}

// Fallback if ws too small for the packed table: raw weights, 1 row/thread.
__global__ __launch_bounds__(256) void henon_raw(
    const float4* __restrict__ z, const float* __restrict__ W_in,
    const float* __restrict__ W_out, const float* __restrict__ b_in,
    const float* __restrict__ eta, float4* __restrict__ out, int batch) {
  int idx = blockIdx.x * blockDim.x + threadIdx.x;
  int stride = gridDim.x * blockDim.x;
  float e0 = eta[0], e1 = eta[1];
  for (int row = idx; row < batch; row += stride) {
    float4 v = z[row];
    float X0 = v.x, X1 = v.y, Y0 = v.z, Y1 = v.w;
    for (int it = 0; it < 4; ++it) {
      float g0 = 0.f, g1 = 0.f;
#pragma unroll
      for (int i = 0; i < NI; ++i) {
        float w0 = W_in[i], w1 = W_in[NI + i];
        float a = fmaf(Y0, w0, fmaf(Y1, w1, b_in[i]));
        float x = a * a;
        float p = fmaf(x, D5, D4);
        p = fmaf(p, x, D3);
        p = fmaf(p, x, D2);
        p = fmaf(p, x, 1.0f);
        p = fmaf(p, x, 1.0f);
        float s = __builtin_amdgcn_rcpf(p) * W_out[i];
        g0 = fmaf(s, w0, g0);
        g1 = fmaf(s, w1, g1);
      }
      float nX0 = Y0 + e0, nX1 = Y1 + e1;
      Y0 = g0 - X0;
      Y1 = g1 - X1;
      X0 = nX0;
      X1 = nX1;
    }
    out[row] = make_float4(X0, X1, Y0, Y1);
  }
}

extern "C" void kernel_launch(void* const* d_in, const int* in_sizes, int n_in,
                              void* d_out, int out_size, void* d_ws, size_t ws_size,
                              hipStream_t stream) {
  const float4* z = (const float4*)d_in[0];
  const float* W_in = (const float*)d_in[1];
  const float* W_out = (const float*)d_in[2];
  const float* b_in = (const float*)d_in[3];
  const float* eta = (const float*)d_in[4];
  float4* out = (float4*)d_out;

  int batch = in_sizes[0] / 4;  // 2,000,000 rows

  if (ws_size >= (5 * NI + 2) * sizeof(float)) {
    float* P = (float*)d_ws;
    henon_prep<<<1, 64, 0, stream>>>(W_in, W_out, b_in, eta, P);
    int ngroups = (batch + 3) >> 2;
    int blocks = (ngroups + 255) / 256;
    henon4<<<blocks, 256, 0, stream>>>(z, P, out, batch);
  } else {
    int blocks = (batch + 255) / 256;
    henon_raw<<<blocks, 256, 0, stream>>>(z, W_in, W_out, b_in, eta, out, batch);
  }
}

// Round 3
// 218.414 us; speedup vs baseline: 1.2241x; 1.1478x over previous
//
#include <hip/hip_runtime.h>

// HenonLayer: 4x { t=tanh(Y@W_in+b); grad=((1-t^2)*W_out)@W_in.T; X'=Y+eta; Y'=-X+grad }
// B=2e6, DIM=2, NI=64, fp32. eps=1.
//
// Round-3: force v_pk_fma_f32 via ext_vector_type(2) + __builtin_elementwise_fma.
// Constants stored as DUPLICATED float2 pairs -> s_load_dwordx2 -> SGPR pair is a
// legal single VOP3P scalar operand (no v_mov duplication). 8 rows/thread.
// sech^2(a) = rcp(cosh^2(a)), cosh^2 = deg-5 all-positive Taylor in x=a^2
// (monotone >= 1, saturates cleanly, no branches; abs err <= ~3e-4).

#define NI 64

#define D5 1.410934744e-4f
#define D4 3.174603175e-3f
#define D3 4.444444444e-2f
#define D2 3.333333333e-1f

typedef float v2f __attribute__((ext_vector_type(2)));

__device__ __forceinline__ v2f splat(float s) { return (v2f){s, s}; }
__device__ __forceinline__ v2f vfma(v2f a, v2f b, v2f c) {
  return __builtin_elementwise_fma(a, b, c);
}
__device__ __forceinline__ v2f vrcp(v2f a) {
  v2f r;
  r.x = __builtin_amdgcn_rcpf(a.x);
  r.y = __builtin_amdgcn_rcpf(a.y);
  return r;
}

// d_ws table (floats): [0:128) w0 pairs | [128:256) w1 pairs | [256:384) b pairs
// | [384:512) c0 pairs | [512:640) c1 pairs | [640],[641] eta
__global__ __launch_bounds__(64) void henon_prep(
    const float* __restrict__ W_in, const float* __restrict__ W_out,
    const float* __restrict__ b_in, const float* __restrict__ eta,
    float* __restrict__ P) {
  int i = threadIdx.x;
  float w0 = W_in[i];
  float w1 = W_in[NI + i];
  float b = b_in[i];
  float wo = W_out[i];
  P[2 * i] = w0;       P[2 * i + 1] = w0;
  P[128 + 2 * i] = w1; P[128 + 2 * i + 1] = w1;
  P[256 + 2 * i] = b;  P[256 + 2 * i + 1] = b;
  float c0 = wo * w0, c1 = wo * w1;
  P[384 + 2 * i] = c0; P[384 + 2 * i + 1] = c0;
  P[512 + 2 * i] = c1; P[512 + 2 * i + 1] = c1;
  if (i < 2) P[640 + i] = eta[i];
}

__global__ __launch_bounds__(256) void henon8(
    const float4* __restrict__ z, const float* __restrict__ P,
    float4* __restrict__ out, int batch) {
  const v2f* __restrict__ Pw0 = (const v2f*)P;
  const v2f* __restrict__ Pw1 = (const v2f*)(P + 128);
  const v2f* __restrict__ Pb  = (const v2f*)(P + 256);
  const v2f* __restrict__ Pc0 = (const v2f*)(P + 384);
  const v2f* __restrict__ Pc1 = (const v2f*)(P + 512);
  float e0 = P[640], e1 = P[641];

  int tid = blockIdx.x * blockDim.x + threadIdx.x;
  int nthr = gridDim.x * blockDim.x;
  int ngroups = batch >> 3;

  for (int g = tid; g < ngroups; g += nthr) {
    int r = g << 3;
    float4 v[8];
#pragma unroll
    for (int k = 0; k < 8; ++k) v[k] = z[r + k];

    v2f X0[4], X1[4], Y0[4], Y1[4];
#pragma unroll
    for (int p = 0; p < 4; ++p) {
      X0[p] = (v2f){v[2 * p].x, v[2 * p + 1].x};
      X1[p] = (v2f){v[2 * p].y, v[2 * p + 1].y};
      Y0[p] = (v2f){v[2 * p].z, v[2 * p + 1].z};
      Y1[p] = (v2f){v[2 * p].w, v[2 * p + 1].w};
    }

    for (int it = 0; it < 4; ++it) {
      v2f g0[4], g1[4];
#pragma unroll
      for (int p = 0; p < 4; ++p) { g0[p] = splat(0.f); g1[p] = splat(0.f); }
#pragma unroll
      for (int i = 0; i < NI; ++i) {
        v2f w0 = Pw0[i], w1 = Pw1[i], b = Pb[i];
        v2f c0 = Pc0[i], c1 = Pc1[i];
#pragma unroll
        for (int p = 0; p < 4; ++p) {
          v2f a = vfma(Y0[p], w0, vfma(Y1[p], w1, b));
          v2f x = a * a;
          v2f q = vfma(x, splat(D5), splat(D4));
          q = vfma(q, x, splat(D3));
          q = vfma(q, x, splat(D2));
          q = vfma(q, x, splat(1.0f));
          q = vfma(q, x, splat(1.0f));
          v2f s = vrcp(q);
          g0[p] = vfma(s, c0, g0[p]);
          g1[p] = vfma(s, c1, g1[p]);
        }
      }
#pragma unroll
      for (int p = 0; p < 4; ++p) {
        v2f nX0 = Y0[p] + splat(e0);
        v2f nX1 = Y1[p] + splat(e1);
        Y0[p] = g0[p] - X0[p];
        Y1[p] = g1[p] - X1[p];
        X0[p] = nX0;
        X1[p] = nX1;
      }
    }
#pragma unroll
    for (int p = 0; p < 4; ++p) {
      out[r + 2 * p]     = make_float4(X0[p].x, X1[p].x, Y0[p].x, Y1[p].x);
      out[r + 2 * p + 1] = make_float4(X0[p].y, X1[p].y, Y0[p].y, Y1[p].y);
    }
  }

  // Tail rows (batch % 8), scalar path.
  int tail = batch & 7;
  if (tail && tid < tail) {
    int row = (ngroups << 3) + tid;
    float4 v = z[row];
    float X0 = v.x, X1 = v.y, Y0 = v.z, Y1 = v.w;
    for (int it = 0; it < 4; ++it) {
      float g0 = 0.f, g1 = 0.f;
      for (int i = 0; i < NI; ++i) {
        float a = fmaf(Y0, Pw0[i].x, fmaf(Y1, Pw1[i].x, Pb[i].x));
        float x = a * a;
        float q = fmaf(x, D5, D4);
        q = fmaf(q, x, D3);
        q = fmaf(q, x, D2);
        q = fmaf(q, x, 1.0f);
        q = fmaf(q, x, 1.0f);
        float s = __builtin_amdgcn_rcpf(q);
        g0 = fmaf(s, Pc0[i].x, g0);
        g1 = fmaf(s, Pc1[i].x, g1);
      }
      float nX0 = Y0 + e0, nX1 = Y1 + e1;
      Y0 = g0 - X0;
      Y1 = g1 - X1;
      X0 = nX0;
      X1 = nX1;
    }
    out[row] = make_float4(X0, X1, Y0, Y1);
  }
}

// Fallback if ws too small for the table: raw weights, 1 row/thread.
__global__ __launch_bounds__(256) void henon_raw(
    const float4* __restrict__ z, const float* __restrict__ W_in,
    const float* __restrict__ W_out, const float* __restrict__ b_in,
    const float* __restrict__ eta, float4* __restrict__ out, int batch) {
  int idx = blockIdx.x * blockDim.x + threadIdx.x;
  int stride = gridDim.x * blockDim.x;
  float e0 = eta[0], e1 = eta[1];
  for (int row = idx; row < batch; row += stride) {
    float4 v = z[row];
    float X0 = v.x, X1 = v.y, Y0 = v.z, Y1 = v.w;
    for (int it = 0; it < 4; ++it) {
      float g0 = 0.f, g1 = 0.f;
#pragma unroll
      for (int i = 0; i < NI; ++i) {
        float w0 = W_in[i], w1 = W_in[NI + i];
        float a = fmaf(Y0, w0, fmaf(Y1, w1, b_in[i]));
        float x = a * a;
        float q = fmaf(x, D5, D4);
        q = fmaf(q, x, D3);
        q = fmaf(q, x, D2);
        q = fmaf(q, x, 1.0f);
        q = fmaf(q, x, 1.0f);
        float s = __builtin_amdgcn_rcpf(q) * W_out[i];
        g0 = fmaf(s, w0, g0);
        g1 = fmaf(s, w1, g1);
      }
      float nX0 = Y0 + e0, nX1 = Y1 + e1;
      Y0 = g0 - X0;
      Y1 = g1 - X1;
      X0 = nX0;
      X1 = nX1;
    }
    out[row] = make_float4(X0, X1, Y0, Y1);
  }
}

extern "C" void kernel_launch(void* const* d_in, const int* in_sizes, int n_in,
                              void* d_out, int out_size, void* d_ws, size_t ws_size,
                              hipStream_t stream) {
  const float4* z = (const float4*)d_in[0];
  const float* W_in = (const float*)d_in[1];
  const float* W_out = (const float*)d_in[2];
  const float* b_in = (const float*)d_in[3];
  const float* eta = (const float*)d_in[4];
  float4* out = (float4*)d_out;

  int batch = in_sizes[0] / 4;  // 2,000,000 rows

  if (ws_size >= 642 * sizeof(float)) {
    float* P = (float*)d_ws;
    henon_prep<<<1, 64, 0, stream>>>(W_in, W_out, b_in, eta, P);
    int ngroups = (batch + 7) >> 3;
    int blocks = (ngroups + 255) / 256;
    henon8<<<blocks, 256, 0, stream>>>(z, P, out, batch);
  } else {
    int blocks = (batch + 255) / 256;
    henon_raw<<<blocks, 256, 0, stream>>>(z, W_in, W_out, b_in, eta, out, batch);
  }
}